// Round 1
// baseline (431.474 us; speedup 1.0000x reference)
//
#include <hip/hip_runtime.h>
#include <hip/hip_bf16.h>
#include <stdint.h>

#define NB 8192
#define NE 210
#define NS 7
#define NEXP 217
#define NI 8
#define H 128
#define BT 256
#define NTILE (NB / BT)          // 32
#define BLOB_STRIDE 73728        // 8K (W1t) + 32K (Wh0t) + 32K (Wh1t)
#define WH0_OFF 8192
#define WH1_OFF 40960
#define SMEM_BYTES (73728 + 65536)

// ws layout (bytes)
#define O_BLOB 0u
#define O_F    16000000u
#define O_FS   43525120u
#define O_PART 43754496u

typedef __attribute__((ext_vector_type(8))) short bf16x8;
typedef __attribute__((ext_vector_type(4))) float f32x4;

__device__ __forceinline__ unsigned short f2bf(float f) {
  unsigned u = __float_as_uint(f);
  u += 0x7fffu + ((u >> 16) & 1u);
  return (unsigned short)(u >> 16);
}
__device__ __forceinline__ float bf2f(unsigned short h) {
  return __uint_as_float(((unsigned)h) << 16);
}
__device__ __forceinline__ float fast_tanh(float x) {
  // tanh(x) = 1 - 2/(1 + 2^(x*2*log2(e))); saturates correctly for |x| large
  float e = __builtin_amdgcn_exp2f(2.8853900817779268f * x);
  return 1.0f - 2.0f * __builtin_amdgcn_rcpf(1.0f + e);
}
__device__ __forceinline__ void glds16(const void* g, void* l) {
  __builtin_amdgcn_global_load_lds(
      (const __attribute__((address_space(1))) unsigned int*)g,
      (__attribute__((address_space(3))) unsigned int*)l, 16, 0, 0);
}

// ---------------- weight pack: f32 -> bf16, transposed [n][k], swizzled ----
// blob per expert: W1t (128 rows x 32 k, 64B rows, chunk c holds k-chunk c^(n&3))
//                  WhLt (128 rows x 128 k, 256B rows, chunk c holds k-chunk c^(n&7))
union Row16 { int4 v[16]; unsigned short u[128]; };

__global__ __launch_bounds__(128) void k_pack(
    const float* __restrict__ W1, const float* __restrict__ Wh,
    const float* __restrict__ W1s, const float* __restrict__ Whs,
    uint8_t* __restrict__ blob) {
  int bid = blockIdx.x;
  int e = bid / 3, sec = bid % 3;
  int n = threadIdx.x;
  uint8_t* be = blob + (size_t)e * BLOB_STRIDE;
  bool big = e < NE;
  int s = e - NE;
  if (sec == 0) {
    union { int4 v[4]; unsigned short u[32]; } row;
    for (int c = 0; c < 4; ++c) row.v[c] = make_int4(0, 0, 0, 0);
    if (big) {
      for (int k = 0; k < NI; ++k) row.u[k] = f2bf(W1[((size_t)e * NI + k) * H + n]);
    } else {
      for (int k = 0; k < 2; ++k) row.u[k] = f2bf(W1s[((size_t)s * 2 + k) * H + n]);
    }
    int4* dst = (int4*)(be + n * 64);
    for (int c = 0; c < 4; ++c) dst[c] = row.v[c ^ (n & 3)];
  } else {
    int l = sec - 1;
    Row16 row;
    if (big) {
      for (int k = 0; k < H; ++k)
        row.u[k] = f2bf(Wh[(((size_t)l * NE + e) * H + k) * H + n]);
    } else {
      for (int k = 0; k < H; ++k)
        row.u[k] = f2bf(Whs[(((size_t)l * NS + s) * H + k) * H + n]);
    }
    int4* dst = (int4*)(be + (l ? WH1_OFF : WH0_OFF) + n * 256);
    for (int c = 0; c < 16; ++c) dst[c] = row.v[c ^ (n & 7)];
  }
}

// ---------------- F build: normalize + gather, bf16 ----------------------
__global__ __launch_bounds__(256) void k_fbuild(
    const float* __restrict__ F_dist, const float* __restrict__ F_cos,
    const float* __restrict__ F_sin,
    const float* __restrict__ Zd, const float* __restrict__ Zc,
    const float* __restrict__ Zs,
    const int* __restrict__ IDX3, const int* __restrict__ IDX5,
    uint16_t* __restrict__ F, uint16_t* __restrict__ Fs) {
  int bid = blockIdx.x;
  int e = bid >> 5, tile = bid & 31;
  int b = tile * 256 + threadIdx.x;
  if (e < NE) {
    float cv = (F_cos[(size_t)b * NE + e] - Zc[e]) / Zc[NE + e];
    float sv = (F_sin[(size_t)b * NE + e] - Zs[e]) / Zs[NE + e];
    union { int4 v; unsigned short u[8]; } o;
    for (int j = 0; j < 6; ++j) {
      int id = IDX3[e * 6 + j];
      float x = (F_dist[(size_t)b * 45 + id] - Zd[id]) / Zd[45 + id];
      o.u[j] = f2bf(x);
    }
    o.u[6] = f2bf(cv);
    o.u[7] = f2bf(sv);
    *(int4*)(F + ((size_t)e * NB + b) * 8) = o.v;
  } else {
    int s = e - NE;
    int id = IDX5[s];
    float cv = (F_cos[(size_t)b * NE + id] - Zc[id]) / Zc[NE + id];
    float sv = (F_sin[(size_t)b * NE + id] - Zs[id]) / Zs[NE + id];
    unsigned o = (unsigned)f2bf(cv) | ((unsigned)f2bf(sv) << 16);
    *(unsigned*)(Fs + ((size_t)s * NB + b) * 2) = o;
  }
}

// ---------------- main: 3-layer MLP per (expert, 256-row tile) ------------
__global__ __launch_bounds__(512) void k_main(
    const uint8_t* __restrict__ blob,
    const uint16_t* __restrict__ F, const uint16_t* __restrict__ Fs,
    const float* __restrict__ b1, const float* __restrict__ bh,
    const float* __restrict__ Wo, const float* __restrict__ bo,
    const float* __restrict__ b1s, const float* __restrict__ bhs,
    const float* __restrict__ Wos, const float* __restrict__ bos,
    float* __restrict__ partial) {
  extern __shared__ __attribute__((aligned(16))) uint8_t smem[];
  uint8_t* wbuf = smem;            // 73728
  uint8_t* hbuf = smem + 73728;    // 256 rows x 256 B

  int bid = blockIdx.x;
  const int TOT = NEXP * NTILE;    // 6944, divisible by 8
  int lb = (bid & 7) * (TOT >> 3) + (bid >> 3);   // XCD-chunked swizzle
  int e = lb >> 5;
  int tile = lb & 31;
  int brow = tile * BT;

  int t = threadIdx.x;
  int wid = t >> 6, lane = t & 63;
  int col0 = lane & 15, grp = lane >> 4;
  int rg = wid >> 1, cg = wid & 1;   // 4 row-groups x 2 col-groups, 64x64/wave

  bool big = e < NE;
  int s = e - NE;

  // async weight staging: 72 x 1KB chunks
  const uint8_t* src = blob + (size_t)e * BLOB_STRIDE;
  for (int c = wid; c < 72; c += 8)
    glds16(src + c * 1024 + lane * 16, wbuf + c * 1024);

  // F staging into hbuf rows (k 0..7 data, k 8..31 zeros), swizzled
  if (t < 256) {
    int r = t;
    uint8_t* dst = hbuf + r * 256 + ((r & 7) << 4);
    if (big) {
      *(int4*)dst = *(const int4*)(F + ((size_t)e * NB + brow + r) * 8);
    } else {
      unsigned v = *(const unsigned*)(Fs + ((size_t)s * NB + brow + r) * 2);
      *(int4*)dst = make_int4((int)v, 0, 0, 0);
    }
  } else {
    int r = t - 256;
    for (int c = 1; c < 4; ++c)
      *(int4*)(hbuf + r * 256 + ((c * 16) ^ ((r & 7) << 4))) = make_int4(0, 0, 0, 0);
  }

  // biases for this wave's 4 col-tiles
  float bia1[4], biah0[4], biah1[4];
#pragma unroll
  for (int nt = 0; nt < 4; ++nt) {
    int cc = cg * 64 + nt * 16 + col0;
    bia1[nt]  = big ? b1[(size_t)e * H + cc]            : b1s[(size_t)s * H + cc];
    biah0[nt] = big ? bh[((size_t)e) * H + cc]          : bhs[((size_t)s) * H + cc];
    biah1[nt] = big ? bh[((size_t)NE + e) * H + cc]     : bhs[((size_t)NS + s) * H + cc];
  }
  __syncthreads();   // drains glds (vmcnt) + lds writes

  f32x4 acc[4][4];

  // ---- layer 1: K=32 (k>=8 zero-padded) ----
  {
    bf16x8 af[4];
#pragma unroll
    for (int mt = 0; mt < 4; ++mt) {
      int r = rg * 64 + mt * 16 + col0;
      af[mt] = *(const bf16x8*)(hbuf + r * 256 + ((grp * 16) ^ ((r & 7) << 4)));
    }
#pragma unroll
    for (int nt = 0; nt < 4; ++nt) {
      int n = cg * 64 + nt * 16 + col0;
      bf16x8 bf = *(const bf16x8*)(wbuf + n * 64 + ((grp * 16) ^ ((n & 3) << 4)));
      f32x4 c0 = {bia1[nt], bia1[nt], bia1[nt], bia1[nt]};
#pragma unroll
      for (int mt = 0; mt < 4; ++mt)
        acc[mt][nt] = __builtin_amdgcn_mfma_f32_16x16x32_bf16(af[mt], bf, c0, 0, 0, 0);
    }
    __syncthreads();   // all hbuf reads done
#pragma unroll
    for (int mt = 0; mt < 4; ++mt)
#pragma unroll
      for (int nt = 0; nt < 4; ++nt)
#pragma unroll
        for (int j = 0; j < 4; ++j) {
          int drow = rg * 64 + mt * 16 + grp * 4 + j;
          int dcol = cg * 64 + nt * 16 + col0;
          *(unsigned short*)(hbuf + drow * 256 + ((dcol * 2) ^ ((drow & 7) << 4))) =
              f2bf(fast_tanh(acc[mt][nt][j]));
        }
    __syncthreads();
  }

  // ---- hidden layers: K=128 ----
#pragma unroll
  for (int layer = 0; layer < 2; ++layer) {
    int wOff = layer ? WH1_OFF : WH0_OFF;
    const float* bia = layer ? biah1 : biah0;
#pragma unroll
    for (int mt = 0; mt < 4; ++mt)
#pragma unroll
      for (int nt = 0; nt < 4; ++nt) {
        f32x4 c0 = {bia[nt], bia[nt], bia[nt], bia[nt]};
        acc[mt][nt] = c0;
      }
#pragma unroll
    for (int kk = 0; kk < 4; ++kk) {
      bf16x8 af[4];
#pragma unroll
      for (int mt = 0; mt < 4; ++mt) {
        int r = rg * 64 + mt * 16 + col0;
        af[mt] = *(const bf16x8*)(hbuf + r * 256 + ((kk * 64 + grp * 16) ^ ((r & 7) << 4)));
      }
#pragma unroll
      for (int nt = 0; nt < 4; ++nt) {
        int n = cg * 64 + nt * 16 + col0;
        bf16x8 bf = *(const bf16x8*)(wbuf + wOff + n * 256 +
                                     ((kk * 64 + grp * 16) ^ ((n & 7) << 4)));
#pragma unroll
        for (int mt = 0; mt < 4; ++mt)
          acc[mt][nt] = __builtin_amdgcn_mfma_f32_16x16x32_bf16(af[mt], bf, acc[mt][nt], 0, 0, 0);
      }
    }
    __syncthreads();
#pragma unroll
    for (int mt = 0; mt < 4; ++mt)
#pragma unroll
      for (int nt = 0; nt < 4; ++nt)
#pragma unroll
        for (int j = 0; j < 4; ++j) {
          int drow = rg * 64 + mt * 16 + grp * 4 + j;
          int dcol = cg * 64 + nt * 16 + col0;
          *(unsigned short*)(hbuf + drow * 256 + ((dcol * 2) ^ ((drow & 7) << 4))) =
              f2bf(fast_tanh(acc[mt][nt][j]));
        }
    __syncthreads();
  }

  // ---- output layer: per-row dot with Wo + bo -> partial[e][b] ----
  const float* wo = big ? (Wo + (size_t)e * H) : (Wos + (size_t)s * H);
  float bout = big ? bo[e] : bos[s];
#pragma unroll
  for (int p = 0; p < 2; ++p) {
    int r = wid * 32 + p * 16 + col0;
    float sum = 0.f;
#pragma unroll
    for (int c = 0; c < 4; ++c) {
      bf16x8 hv = *(const bf16x8*)(hbuf + r * 256 + ((grp * 64 + c * 16) ^ ((r & 7) << 4)));
#pragma unroll
      for (int j = 0; j < 8; ++j)
        sum += bf2f((unsigned short)hv[j]) * wo[grp * 32 + c * 8 + j];
    }
    sum += __shfl_xor(sum, 16);
    sum += __shfl_xor(sum, 32);
    if (grp == 0)
      partial[(size_t)e * NB + brow + r] = sum + bout;
  }
}

// ---------------- reduce over experts ------------------------------------
__global__ __launch_bounds__(256) void k_reduce(const float* __restrict__ partial,
                                                float* __restrict__ out) {
  int b = blockIdx.x * 256 + threadIdx.x;
  float s = 0.f;
  for (int e = 0; e < NEXP; ++e) s += partial[(size_t)e * NB + b];
  out[b] = s;
}

extern "C" void kernel_launch(void* const* d_in, const int* in_sizes, int n_in,
                              void* d_out, int out_size, void* d_ws, size_t ws_size,
                              hipStream_t stream) {
  const float* F_dist = (const float*)d_in[0];
  const float* F_cos  = (const float*)d_in[1];
  const float* F_sin  = (const float*)d_in[2];
  // d_in[3] F_angle unused by reference
  const float* Zd  = (const float*)d_in[4];
  const float* Zc  = (const float*)d_in[5];
  const float* Zs  = (const float*)d_in[6];
  const int* IDX3  = (const int*)d_in[7];
  const int* IDX5  = (const int*)d_in[8];
  const float* W1  = (const float*)d_in[9];
  const float* b1  = (const float*)d_in[10];
  const float* Wh  = (const float*)d_in[11];
  const float* bh  = (const float*)d_in[12];
  const float* Wo  = (const float*)d_in[13];
  const float* bo  = (const float*)d_in[14];
  const float* W1s = (const float*)d_in[15];
  const float* b1s = (const float*)d_in[16];
  const float* Whs = (const float*)d_in[17];
  const float* bhs = (const float*)d_in[18];
  const float* Wos = (const float*)d_in[19];
  const float* bos = (const float*)d_in[20];

  uint8_t* ws = (uint8_t*)d_ws;
  uint8_t* blob = ws + O_BLOB;
  uint16_t* F   = (uint16_t*)(ws + O_F);
  uint16_t* Fs  = (uint16_t*)(ws + O_FS);
  float* partial = (float*)(ws + O_PART);

  hipFuncSetAttribute(reinterpret_cast<const void*>(k_main),
                      hipFuncAttributeMaxDynamicSharedMemorySize, SMEM_BYTES);

  k_pack<<<NEXP * 3, 128, 0, stream>>>(W1, Wh, W1s, Whs, blob);
  k_fbuild<<<NEXP * 32, 256, 0, stream>>>(F_dist, F_cos, F_sin, Zd, Zc, Zs,
                                          IDX3, IDX5, F, Fs);
  k_main<<<NEXP * NTILE, 512, SMEM_BYTES, stream>>>(blob, F, Fs, b1, bh, Wo, bo,
                                                    b1s, bhs, Wos, bos, partial);
  k_reduce<<<NB / 256, 256, 0, stream>>>(partial, (float*)d_out);
}

// Round 2
// 361.036 us; speedup vs baseline: 1.1951x; 1.1951x over previous
//
#include <hip/hip_runtime.h>
#include <hip/hip_bf16.h>
#include <stdint.h>

#define NB 8192
#define NE 210
#define NS 7
#define NEXP 217
#define NI 8
#define H 128
#define BT 256
#define NTILE (NB / BT)          // 32
#define BLOB_STRIDE 73728        // 8K (W1t) + 32K (Wh0t) + 32K (Wh1t)
#define WH0_OFF 8192
#define WH1_OFF 40960
#define SMEM_BYTES (73728 + 65536)

// ws layout (bytes)
#define O_BLOB 0u
#define O_F    16000000u
#define O_FS   43525120u
#define O_PART 43754496u

typedef __attribute__((ext_vector_type(8))) short bf16x8;
typedef __attribute__((ext_vector_type(4))) float f32x4;

__device__ __forceinline__ unsigned short f2bf(float f) {
  unsigned u = __float_as_uint(f);
  u += 0x7fffu + ((u >> 16) & 1u);
  return (unsigned short)(u >> 16);
}
__device__ __forceinline__ float bf2f(unsigned short h) {
  return __uint_as_float(((unsigned)h) << 16);
}
__device__ __forceinline__ float fast_tanh(float x) {
  // tanh(x) = 1 - 2/(1 + 2^(x*2*log2(e))); saturates correctly for |x| large
  float e = __builtin_amdgcn_exp2f(2.8853900817779268f * x);
  return 1.0f - 2.0f * __builtin_amdgcn_rcpf(1.0f + e);
}
__device__ __forceinline__ unsigned pk_bf16(float a, float b) {
  unsigned r;
  asm("v_cvt_pk_bf16_f32 %0, %1, %2" : "=v"(r) : "v"(a), "v"(b));
  return r;
}
__device__ __forceinline__ void glds16(const void* g, void* l) {
  __builtin_amdgcn_global_load_lds(
      (const __attribute__((address_space(1))) unsigned int*)g,
      (__attribute__((address_space(3))) unsigned int*)l, 16, 0, 0);
}

// ---------------- weight pack: f32 -> bf16, transposed [out][in], swizzled --
// W1t: 128 rows x 64B (K=32 zero-padded), slot c holds k-chunk c^(n&3)
// WhLt: 128 rows x 256B (K=128), slot c holds k-chunk c^(n&15)
union Row16 { int4 v[16]; unsigned short u[128]; };

__global__ __launch_bounds__(128) void k_pack(
    const float* __restrict__ W1, const float* __restrict__ Wh,
    const float* __restrict__ W1s, const float* __restrict__ Whs,
    uint8_t* __restrict__ blob) {
  int bid = blockIdx.x;
  int e = bid / 3, sec = bid % 3;
  int n = threadIdx.x;
  uint8_t* be = blob + (size_t)e * BLOB_STRIDE;
  bool big = e < NE;
  int s = e - NE;
  if (sec == 0) {
    union { int4 v[4]; unsigned short u[32]; } row;
    for (int c = 0; c < 4; ++c) row.v[c] = make_int4(0, 0, 0, 0);
    if (big) {
      for (int k = 0; k < NI; ++k) row.u[k] = f2bf(W1[((size_t)e * NI + k) * H + n]);
    } else {
      for (int k = 0; k < 2; ++k) row.u[k] = f2bf(W1s[((size_t)s * 2 + k) * H + n]);
    }
    int4* dst = (int4*)(be + n * 64);
    for (int c = 0; c < 4; ++c) dst[c] = row.v[c ^ (n & 3)];
  } else {
    int l = sec - 1;
    Row16 row;
    if (big) {
      for (int k = 0; k < H; ++k)
        row.u[k] = f2bf(Wh[(((size_t)l * NE + e) * H + k) * H + n]);
    } else {
      for (int k = 0; k < H; ++k)
        row.u[k] = f2bf(Whs[(((size_t)l * NS + s) * H + k) * H + n]);
    }
    int4* dst = (int4*)(be + (l ? WH1_OFF : WH0_OFF) + n * 256);
    for (int c = 0; c < 16; ++c) dst[c] = row.v[c ^ (n & 15)];
  }
}

// ---------------- F build: normalize + gather, bf16 ----------------------
__global__ __launch_bounds__(256) void k_fbuild(
    const float* __restrict__ F_dist, const float* __restrict__ F_cos,
    const float* __restrict__ F_sin,
    const float* __restrict__ Zd, const float* __restrict__ Zc,
    const float* __restrict__ Zs,
    const int* __restrict__ IDX3, const int* __restrict__ IDX5,
    uint16_t* __restrict__ F, uint16_t* __restrict__ Fs) {
  int bid = blockIdx.x;
  int e = bid >> 5, tile = bid & 31;
  int b = tile * 256 + threadIdx.x;
  if (e < NE) {
    float cv = (F_cos[(size_t)b * NE + e] - Zc[e]) / Zc[NE + e];
    float sv = (F_sin[(size_t)b * NE + e] - Zs[e]) / Zs[NE + e];
    union { int4 v; unsigned short u[8]; } o;
    for (int j = 0; j < 6; ++j) {
      int id = IDX3[e * 6 + j];
      float x = (F_dist[(size_t)b * 45 + id] - Zd[id]) / Zd[45 + id];
      o.u[j] = f2bf(x);
    }
    o.u[6] = f2bf(cv);
    o.u[7] = f2bf(sv);
    *(int4*)(F + ((size_t)e * NB + b) * 8) = o.v;
  } else {
    int s = e - NE;
    int id = IDX5[s];
    float cv = (F_cos[(size_t)b * NE + id] - Zc[id]) / Zc[NE + id];
    float sv = (F_sin[(size_t)b * NE + id] - Zs[id]) / Zs[NE + id];
    unsigned o = (unsigned)f2bf(cv) | ((unsigned)f2bf(sv) << 16);
    *(unsigned*)(Fs + ((size_t)s * NB + b) * 2) = o;
  }
}

// ---------------- main: 3-layer MLP per (expert, 256-row tile) ------------
// Orientation: A = W^T (M=features), B = h (N=batch cols).
// Each wave owns batch cols [w*32, w*32+32) exclusively: staging, B-reads,
// epilogue writes, and output dot are all wave-local -> no inner barriers.
__device__ __forceinline__ void tanh_store(f32x4 (&acc)[8][2], uint8_t* hbuf,
                                           int nrow0, int col0, int grp, int swz) {
#pragma unroll
  for (int mt = 0; mt < 8; ++mt)
#pragma unroll
    for (int nt = 0; nt < 2; ++nt) {
      float t0 = fast_tanh(acc[mt][nt][0]);
      float t1 = fast_tanh(acc[mt][nt][1]);
      float t2 = fast_tanh(acc[mt][nt][2]);
      float t3 = fast_tanh(acc[mt][nt][3]);
      uint2 pv = make_uint2(pk_bf16(t0, t1), pk_bf16(t2, t3));
      int n = nrow0 + nt * 16 + col0;
      *(uint2*)(hbuf + n * 256 + ((mt * 32 + grp * 8) ^ swz)) = pv;
    }
}

__global__ __launch_bounds__(512) void k_main(
    const uint8_t* __restrict__ blob,
    const uint16_t* __restrict__ F, const uint16_t* __restrict__ Fs,
    const float* __restrict__ b1, const float* __restrict__ bh,
    const float* __restrict__ Wo, const float* __restrict__ bo,
    const float* __restrict__ b1s, const float* __restrict__ bhs,
    const float* __restrict__ Wos, const float* __restrict__ bos,
    float* __restrict__ partial) {
  extern __shared__ __attribute__((aligned(16))) uint8_t smem[];
  uint8_t* wbuf = smem;            // 73728
  uint8_t* hbuf = smem + 73728;    // 256 rows x 256 B

  int bid = blockIdx.x;
  const int TOT = NEXP * NTILE;    // 6944, divisible by 8
  int lb = (bid & 7) * (TOT >> 3) + (bid >> 3);   // XCD-chunked swizzle
  int e = lb >> 5;
  int tile = lb & 31;
  int brow = tile * BT;

  int t = threadIdx.x;
  int w = t >> 6, lane = t & 63;
  int col0 = lane & 15, grp = lane >> 4;
  int swz = col0 << 4;             // (row&15)<<4 for all row indices we touch
  int nrow0 = w * 32;

  bool big = e < NE;
  int s = e - NE;

  // async weight staging: 72 x 1KB chunks (cooperative, the only barrier)
  const uint8_t* src = blob + (size_t)e * BLOB_STRIDE;
  for (int c = w; c < 72; c += 8)
    glds16(src + c * 1024 + lane * 16, wbuf + c * 1024);

  // F staging: wave-owned rows, logical k-slots 0..3 (layer-1 K=32)
  {
#pragma unroll
    for (int p = 0; p < 2; ++p) {
      int idx = p * 64 + lane;                 // 0..127 = (row, chunk)
      int r = nrow0 + (idx >> 2);
      int c = idx & 3;
      int4 v = make_int4(0, 0, 0, 0);
      if (c == 0) {
        if (big) {
          v = *(const int4*)(F + ((size_t)e * NB + brow + r) * 8);
        } else {
          unsigned u = *(const unsigned*)(Fs + ((size_t)s * NB + brow + r) * 2);
          v = make_int4((int)u, 0, 0, 0);
        }
      }
      *(int4*)(hbuf + r * 256 + ((c * 16) ^ ((r & 15) << 4))) = v;
    }
  }

  const float* bias1  = big ? b1 + (size_t)e * H : b1s + (size_t)s * H;
  const float* biasH0 = big ? bh + (size_t)e * H : bhs + (size_t)s * H;
  const float* biasH1 = big ? bh + ((size_t)NE + e) * H : bhs + ((size_t)NS + s) * H;
  const float* wo = big ? Wo + (size_t)e * H : Wos + (size_t)s * H;
  float bout = big ? bo[e] : bos[s];

  __syncthreads();   // weights visible to all waves (drains glds vmcnt)

  f32x4 acc[8][2];

  // ---- layer 1: K=32 (zero-padded beyond NI) ----
  {
    bf16x8 aF[8], bF[2];
#pragma unroll
    for (int mt = 0; mt < 8; ++mt) {
      int m = mt * 16 + col0;
      aF[mt] = *(const bf16x8*)(wbuf + m * 64 + ((grp * 16) ^ ((m & 3) << 4)));
    }
#pragma unroll
    for (int nt = 0; nt < 2; ++nt) {
      int n = nrow0 + nt * 16 + col0;
      bF[nt] = *(const bf16x8*)(hbuf + n * 256 + ((grp * 16) ^ swz));
    }
#pragma unroll
    for (int mt = 0; mt < 8; ++mt) {
      f32x4 c0 = *(const f32x4*)(bias1 + mt * 16 + grp * 4);
#pragma unroll
      for (int nt = 0; nt < 2; ++nt)
        acc[mt][nt] = __builtin_amdgcn_mfma_f32_16x16x32_bf16(aF[mt], bF[nt], c0, 0, 0, 0);
    }
    tanh_store(acc, hbuf, nrow0, col0, grp, swz);
  }

  // ---- hidden layers: K=128 ----
#pragma unroll
  for (int layer = 0; layer < 2; ++layer) {
    const uint8_t* wb = wbuf + (layer ? WH1_OFF : WH0_OFF);
    const float* bia = layer ? biasH1 : biasH0;
#pragma unroll
    for (int mt = 0; mt < 8; ++mt) {
      f32x4 c0 = *(const f32x4*)(bia + mt * 16 + grp * 4);
      acc[mt][0] = c0;
      acc[mt][1] = c0;
    }
#pragma unroll
    for (int kk = 0; kk < 4; ++kk) {
      int koff = kk * 64 + grp * 16;
      bf16x8 aF[8];
#pragma unroll
      for (int mt = 0; mt < 8; ++mt) {
        int m = mt * 16 + col0;
        aF[mt] = *(const bf16x8*)(wb + m * 256 + (koff ^ swz));
      }
      bf16x8 bF[2];
#pragma unroll
      for (int nt = 0; nt < 2; ++nt) {
        int n = nrow0 + nt * 16 + col0;
        bF[nt] = *(const bf16x8*)(hbuf + n * 256 + (koff ^ swz));
      }
#pragma unroll
      for (int mt = 0; mt < 8; ++mt)
#pragma unroll
        for (int nt = 0; nt < 2; ++nt)
          acc[mt][nt] = __builtin_amdgcn_mfma_f32_16x16x32_bf16(aF[mt], bF[nt], acc[mt][nt], 0, 0, 0);
    }
    tanh_store(acc, hbuf, nrow0, col0, grp, swz);
  }

  // ---- output layer: wave-local dot h3[r][:] . wo + bo -> partial[e][b] ----
  {
    int r = nrow0 + (lane & 31);
    int half = lane >> 5;
    float sum = 0.f;
#pragma unroll
    for (int c = 0; c < 8; ++c) {
      int kb = half * 128 + c * 16;   // byte offset of 8 feats
      bf16x8 hv = *(const bf16x8*)(hbuf + r * 256 + (kb ^ swz));
      float4 w0 = *(const float4*)(wo + half * 64 + c * 8);
      float4 w1 = *(const float4*)(wo + half * 64 + c * 8 + 4);
      sum += bf2f((unsigned short)hv[0]) * w0.x;
      sum += bf2f((unsigned short)hv[1]) * w0.y;
      sum += bf2f((unsigned short)hv[2]) * w0.z;
      sum += bf2f((unsigned short)hv[3]) * w0.w;
      sum += bf2f((unsigned short)hv[4]) * w1.x;
      sum += bf2f((unsigned short)hv[5]) * w1.y;
      sum += bf2f((unsigned short)hv[6]) * w1.z;
      sum += bf2f((unsigned short)hv[7]) * w1.w;
    }
    sum += __shfl_xor(sum, 32);
    if (half == 0)
      partial[(size_t)e * NB + brow + r] = sum + bout;
  }
}

// ---------------- reduce over experts ------------------------------------
__global__ __launch_bounds__(256) void k_reduce(const float* __restrict__ partial,
                                                float* __restrict__ out) {
  int b = blockIdx.x * 256 + threadIdx.x;
  float s = 0.f;
  for (int e = 0; e < NEXP; ++e) s += partial[(size_t)e * NB + b];
  out[b] = s;
}

extern "C" void kernel_launch(void* const* d_in, const int* in_sizes, int n_in,
                              void* d_out, int out_size, void* d_ws, size_t ws_size,
                              hipStream_t stream) {
  const float* F_dist = (const float*)d_in[0];
  const float* F_cos  = (const float*)d_in[1];
  const float* F_sin  = (const float*)d_in[2];
  // d_in[3] F_angle unused by reference
  const float* Zd  = (const float*)d_in[4];
  const float* Zc  = (const float*)d_in[5];
  const float* Zs  = (const float*)d_in[6];
  const int* IDX3  = (const int*)d_in[7];
  const int* IDX5  = (const int*)d_in[8];
  const float* W1  = (const float*)d_in[9];
  const float* b1  = (const float*)d_in[10];
  const float* Wh  = (const float*)d_in[11];
  const float* bh  = (const float*)d_in[12];
  const float* Wo  = (const float*)d_in[13];
  const float* bo  = (const float*)d_in[14];
  const float* W1s = (const float*)d_in[15];
  const float* b1s = (const float*)d_in[16];
  const float* Whs = (const float*)d_in[17];
  const float* bhs = (const float*)d_in[18];
  const float* Wos = (const float*)d_in[19];
  const float* bos = (const float*)d_in[20];

  uint8_t* ws = (uint8_t*)d_ws;
  uint8_t* blob = ws + O_BLOB;
  uint16_t* F   = (uint16_t*)(ws + O_F);
  uint16_t* Fs  = (uint16_t*)(ws + O_FS);
  float* partial = (float*)(ws + O_PART);

  hipFuncSetAttribute(reinterpret_cast<const void*>(k_main),
                      hipFuncAttributeMaxDynamicSharedMemorySize, SMEM_BYTES);

  k_pack<<<NEXP * 3, 128, 0, stream>>>(W1, Wh, W1s, Whs, blob);
  k_fbuild<<<NEXP * 32, 256, 0, stream>>>(F_dist, F_cos, F_sin, Zd, Zc, Zs,
                                          IDX3, IDX5, F, Fs);
  k_main<<<NEXP * NTILE, 512, SMEM_BYTES, stream>>>(blob, F, Fs, b1, bh, Wo, bo,
                                                    b1s, bhs, Wos, bos, partial);
  k_reduce<<<NB / 256, 256, 0, stream>>>(partial, (float*)d_out);
}

// Round 3
// 291.523 us; speedup vs baseline: 1.4801x; 1.2384x over previous
//
#include <hip/hip_runtime.h>
#include <hip/hip_bf16.h>
#include <stdint.h>

#define NB 8192
#define NE 210
#define NS 7
#define NEXP 217
#define NI 8
#define H 128
#define BT 256
#define NTILE (NB / BT)          // 32
#define BLOB_STRIDE 67584        // 2K W1lin + 32K Wh0t + 32K Wh1t
#define WH0_OFF 2048
#define WH1_OFF 34816
#define SMEM_BYTES 65536         // Wh only -> 2 blocks/CU

// ws layout (bytes)
#define O_BLOB 0u
#define O_F    16000000u
#define O_FS   43525120u
#define O_PART 43754496u

typedef __attribute__((ext_vector_type(8))) short bf16x8;
typedef __attribute__((ext_vector_type(4))) float f32x4;

union I4V { int4 i; bf16x8 v; unsigned u[4]; };

__device__ __forceinline__ unsigned short f2bf(float f) {
  unsigned u = __float_as_uint(f);
  u += 0x7fffu + ((u >> 16) & 1u);
  return (unsigned short)(u >> 16);
}
__device__ __forceinline__ float fast_tanh(float x) {
  // tanh(x) = 1 - 2/(1 + 2^(2*log2(e)*x)); saturates correctly at +-inf
  float e = __builtin_amdgcn_exp2f(2.8853900817779268f * x);
  return 1.0f - 2.0f * __builtin_amdgcn_rcpf(1.0f + e);
}
__device__ __forceinline__ unsigned pk_bf16(float a, float b) {
  unsigned r;
  asm("v_cvt_pk_bf16_f32 %0, %1, %2" : "=v"(r) : "v"(a), "v"(b));
  return r;
}
__device__ __forceinline__ void glds16(const void* g, void* l) {
  __builtin_amdgcn_global_load_lds(
      (const __attribute__((address_space(1))) unsigned int*)g,
      (__attribute__((address_space(3))) unsigned int*)l, 16, 0, 0);
}

// ---- inter-layer transpose in registers ----------------------------------
// acc D-layout: lane(grp,col0): acc[mt][nt][j] = feat mt*16+grp*4+j, col nt*16+col0
// next B-frag bn[nt][kk]: lane supplies feats kk*32+grp*8+j (j=0..7), col0
// word w of bn = P[2kk+(grp>>1)][w&1] taken from lane col0+16*(2(grp&1)+(w>>1))
__device__ __forceinline__ void transition(const f32x4 (&acc)[8][2],
                                           bf16x8 (&bn)[2][4],
                                           int idx0, int idx1, bool hi) {
#pragma unroll
  for (int nt = 0; nt < 2; ++nt)
#pragma unroll
    for (int kk = 0; kk < 4; ++kk) {
      unsigned a0 = pk_bf16(fast_tanh(acc[2 * kk][nt][0]), fast_tanh(acc[2 * kk][nt][1]));
      unsigned a1 = pk_bf16(fast_tanh(acc[2 * kk][nt][2]), fast_tanh(acc[2 * kk][nt][3]));
      unsigned b0 = pk_bf16(fast_tanh(acc[2 * kk + 1][nt][0]), fast_tanh(acc[2 * kk + 1][nt][1]));
      unsigned b1 = pk_bf16(fast_tanh(acc[2 * kk + 1][nt][2]), fast_tanh(acc[2 * kk + 1][nt][3]));
      unsigned uA0 = __builtin_amdgcn_ds_bpermute(idx0, (int)a0);
      unsigned uA1 = __builtin_amdgcn_ds_bpermute(idx0, (int)a1);
      unsigned uA2 = __builtin_amdgcn_ds_bpermute(idx1, (int)a0);
      unsigned uA3 = __builtin_amdgcn_ds_bpermute(idx1, (int)a1);
      unsigned uB0 = __builtin_amdgcn_ds_bpermute(idx0, (int)b0);
      unsigned uB1 = __builtin_amdgcn_ds_bpermute(idx0, (int)b1);
      unsigned uB2 = __builtin_amdgcn_ds_bpermute(idx1, (int)b0);
      unsigned uB3 = __builtin_amdgcn_ds_bpermute(idx1, (int)b1);
      I4V r;
      r.u[0] = hi ? uB0 : uA0;
      r.u[1] = hi ? uB1 : uA1;
      r.u[2] = hi ? uB2 : uA2;
      r.u[3] = hi ? uB3 : uA3;
      bn[nt][kk] = r.v;
    }
}

// ---------------- weight pack ---------------------------------------------
__global__ __launch_bounds__(128) void k_pack(
    const float* __restrict__ W1, const float* __restrict__ Wh,
    const float* __restrict__ W1s, const float* __restrict__ Whs,
    uint8_t* __restrict__ blob) {
  int bid = blockIdx.x;
  int e = bid / 3, sec = bid % 3;
  int n = threadIdx.x;
  uint8_t* be = blob + (size_t)e * BLOB_STRIDE;
  bool big = e < NE;
  int s = e - NE;
  if (sec == 0) {
    // W1 linear: 128 rows x 16B (k0..7), no swizzle
    union { int4 v; unsigned short u[8]; } row;
    row.v = make_int4(0, 0, 0, 0);
    if (big) {
      for (int k = 0; k < NI; ++k) row.u[k] = f2bf(W1[((size_t)e * NI + k) * H + n]);
    } else {
      for (int k = 0; k < 2; ++k) row.u[k] = f2bf(W1s[((size_t)s * 2 + k) * H + n]);
    }
    *(int4*)(be + n * 16) = row.v;
  } else {
    int l = sec - 1;
    union { int4 v[16]; unsigned short u[128]; } row;
    if (big) {
      for (int k = 0; k < H; ++k)
        row.u[k] = f2bf(Wh[(((size_t)l * NE + e) * H + k) * H + n]);
    } else {
      for (int k = 0; k < H; ++k)
        row.u[k] = f2bf(Whs[(((size_t)l * NS + s) * H + k) * H + n]);
    }
    int4* dst = (int4*)(be + (l ? WH1_OFF : WH0_OFF) + n * 256);
    for (int c = 0; c < 16; ++c) dst[c] = row.v[c ^ (n & 15)];
  }
}

// ---------------- F build: normalize + gather, bf16 -----------------------
__global__ __launch_bounds__(256) void k_fbuild(
    const float* __restrict__ F_dist, const float* __restrict__ F_cos,
    const float* __restrict__ F_sin,
    const float* __restrict__ Zd, const float* __restrict__ Zc,
    const float* __restrict__ Zs,
    const int* __restrict__ IDX3, const int* __restrict__ IDX5,
    uint16_t* __restrict__ F, uint16_t* __restrict__ Fs) {
  int bid = blockIdx.x;
  int e = bid >> 5, tile = bid & 31;
  int b = tile * 256 + threadIdx.x;
  if (e < NE) {
    float cv = (F_cos[(size_t)b * NE + e] - Zc[e]) / Zc[NE + e];
    float sv = (F_sin[(size_t)b * NE + e] - Zs[e]) / Zs[NE + e];
    union { int4 v; unsigned short u[8]; } o;
    for (int j = 0; j < 6; ++j) {
      int id = IDX3[e * 6 + j];
      float x = (F_dist[(size_t)b * 45 + id] - Zd[id]) / Zd[45 + id];
      o.u[j] = f2bf(x);
    }
    o.u[6] = f2bf(cv);
    o.u[7] = f2bf(sv);
    *(int4*)(F + ((size_t)e * NB + b) * 8) = o.v;
  } else {
    int s = e - NE;
    int id = IDX5[s];
    float cv = (F_cos[(size_t)b * NE + id] - Zc[id]) / Zc[NE + id];
    float sv = (F_sin[(size_t)b * NE + id] - Zs[id]) / Zs[NE + id];
    unsigned o = (unsigned)f2bf(cv) | ((unsigned)f2bf(sv) << 16);
    *(unsigned*)(Fs + ((size_t)s * NB + b) * 2) = o;
  }
}

// ---------------- main: 3-layer MLP, h entirely in registers --------------
__global__ __launch_bounds__(512, 4) void k_main(
    const uint8_t* __restrict__ blob,
    const uint16_t* __restrict__ F, const uint16_t* __restrict__ Fs,
    const float* __restrict__ b1, const float* __restrict__ bh,
    const float* __restrict__ Wo, const float* __restrict__ bo,
    const float* __restrict__ b1s, const float* __restrict__ bhs,
    const float* __restrict__ Wos, const float* __restrict__ bos,
    float* __restrict__ partial) {
  extern __shared__ __attribute__((aligned(16))) uint8_t smem[];  // 64KB Wh

  int bid = blockIdx.x;
  const int TOT = NEXP * NTILE;    // 6944, divisible by 8
  int lb = (bid & 7) * (TOT >> 3) + (bid >> 3);   // XCD-chunked swizzle
  int e = lb >> 5;
  int tile = lb & 31;
  int brow = tile * BT;

  int t = threadIdx.x;
  int w = t >> 6, lane = t & 63;
  int col0 = lane & 15, grp = lane >> 4;
  int nrow0 = w * 32;
  bool hi = grp >= 2;
  int idx0 = (col0 + ((grp & 1) << 5)) << 2;   // bpermute byte idx, w<2
  int idx1 = idx0 + 64;                        // w>=2 (+16 lanes)

  bool big = e < NE;
  int s = e - NE;
  const uint8_t* be = blob + (size_t)e * BLOB_STRIDE;

  // async Wh staging: 64 x 1KB chunks (the only LDS use; one barrier)
  for (int c = w; c < 64; c += 8)
    glds16(be + WH0_OFF + c * 1024 + lane * 16, smem + c * 1024);

  const float* bias1  = big ? b1 + (size_t)e * H : b1s + (size_t)s * H;
  const float* biasH0 = big ? bh + (size_t)e * H : bhs + (size_t)s * H;
  const float* biasH1 = big ? bh + ((size_t)NE + e) * H : bhs + ((size_t)NS + s) * H;
  const float* wo = big ? Wo + (size_t)e * H : Wos + (size_t)s * H;
  float bout = big ? bo[e] : bos[s];

  f32x4 acc[8][2];

  // ---- layer 1 (K=32, real K=8 -> only grp0 lanes nonzero), no LDS ----
  {
    bf16x8 bf[2];
    {
      I4V z0, z1;
      z0.i = make_int4(0, 0, 0, 0);
      z1.i = make_int4(0, 0, 0, 0);
      if (grp == 0) {
        size_t base = (size_t)e * NB + brow + nrow0 + col0;
        if (big) {
          z0.i = *(const int4*)(F + base * 8);
          z1.i = *(const int4*)(F + (base + 16) * 8);
        } else {
          size_t sb = (size_t)s * NB + brow + nrow0 + col0;
          z0.u[0] = *(const unsigned*)(Fs + sb * 2);
          z1.u[0] = *(const unsigned*)(Fs + (sb + 16) * 2);
        }
      }
      bf[0] = z0.v;
      bf[1] = z1.v;
    }
#pragma unroll
    for (int mt = 0; mt < 8; ++mt) {
      I4V a;
      a.i = make_int4(0, 0, 0, 0);
      if (grp == 0)
        a.i = *(const int4*)(be + (mt * 16 + col0) * 16);
      f32x4 c0 = *(const f32x4*)(bias1 + mt * 16 + grp * 4);
      acc[mt][0] = __builtin_amdgcn_mfma_f32_16x16x32_bf16(a.v, bf[0], c0, 0, 0, 0);
      acc[mt][1] = __builtin_amdgcn_mfma_f32_16x16x32_bf16(a.v, bf[1], c0, 0, 0, 0);
    }
  }

  bf16x8 bn[2][4];
  transition(acc, bn, idx0, idx1, hi);   // tanh + repack, overlaps staging

  __syncthreads();   // weights resident

  // ---- hidden layers (K=128) ----
#pragma unroll
  for (int layer = 0; layer < 2; ++layer) {
    const uint8_t* wb = smem + (layer ? 32768 : 0);
    const float* bia = layer ? biasH1 : biasH0;
#pragma unroll
    for (int mt = 0; mt < 8; ++mt) {
      f32x4 c0 = *(const f32x4*)(bia + mt * 16 + grp * 4);
      acc[mt][0] = c0;
      acc[mt][1] = c0;
    }
#pragma unroll
    for (int kk = 0; kk < 4; ++kk) {
#pragma unroll
      for (int mt = 0; mt < 8; ++mt) {
        bf16x8 aF = *(const bf16x8*)(wb + (mt * 16 + col0) * 256 +
                                     ((((kk << 2) + grp) ^ col0) << 4));
        acc[mt][0] = __builtin_amdgcn_mfma_f32_16x16x32_bf16(aF, bn[0][kk], acc[mt][0], 0, 0, 0);
        acc[mt][1] = __builtin_amdgcn_mfma_f32_16x16x32_bf16(aF, bn[1][kk], acc[mt][1], 0, 0, 0);
      }
    }
    if (layer == 0)
      transition(acc, bn, idx0, idx1, hi);
  }

  // ---- output layer: in-register dot, reduce over grp --------------------
  float sum0 = 0.f, sum1 = 0.f;
#pragma unroll
  for (int mt = 0; mt < 8; ++mt) {
    f32x4 w4 = *(const f32x4*)(wo + mt * 16 + grp * 4);
#pragma unroll
    for (int j = 0; j < 4; ++j) {
      sum0 += fast_tanh(acc[mt][0][j]) * w4[j];
      sum1 += fast_tanh(acc[mt][1][j]) * w4[j];
    }
  }
  sum0 += __shfl_xor(sum0, 16);
  sum0 += __shfl_xor(sum0, 32);
  sum1 += __shfl_xor(sum1, 16);
  sum1 += __shfl_xor(sum1, 32);
  if (grp == 0) {
    size_t base = (size_t)e * NB + brow + nrow0 + col0;
    partial[base] = sum0 + bout;
    partial[base + 16] = sum1 + bout;
  }
}

// ---------------- reduce over experts ------------------------------------
__global__ __launch_bounds__(256) void k_reduce(const float* __restrict__ partial,
                                                float* __restrict__ out) {
  int b = blockIdx.x * 256 + threadIdx.x;
  float s = 0.f;
  for (int e = 0; e < NEXP; ++e) s += partial[(size_t)e * NB + b];
  out[b] = s;
}

extern "C" void kernel_launch(void* const* d_in, const int* in_sizes, int n_in,
                              void* d_out, int out_size, void* d_ws, size_t ws_size,
                              hipStream_t stream) {
  const float* F_dist = (const float*)d_in[0];
  const float* F_cos  = (const float*)d_in[1];
  const float* F_sin  = (const float*)d_in[2];
  // d_in[3] F_angle unused by reference
  const float* Zd  = (const float*)d_in[4];
  const float* Zc  = (const float*)d_in[5];
  const float* Zs  = (const float*)d_in[6];
  const int* IDX3  = (const int*)d_in[7];
  const int* IDX5  = (const int*)d_in[8];
  const float* W1  = (const float*)d_in[9];
  const float* b1  = (const float*)d_in[10];
  const float* Wh  = (const float*)d_in[11];
  const float* bh  = (const float*)d_in[12];
  const float* Wo  = (const float*)d_in[13];
  const float* bo  = (const float*)d_in[14];
  const float* W1s = (const float*)d_in[15];
  const float* b1s = (const float*)d_in[16];
  const float* Whs = (const float*)d_in[17];
  const float* bhs = (const float*)d_in[18];
  const float* Wos = (const float*)d_in[19];
  const float* bos = (const float*)d_in[20];

  uint8_t* ws = (uint8_t*)d_ws;
  uint8_t* blob = ws + O_BLOB;
  uint16_t* F   = (uint16_t*)(ws + O_F);
  uint16_t* Fs  = (uint16_t*)(ws + O_FS);
  float* partial = (float*)(ws + O_PART);

  hipFuncSetAttribute(reinterpret_cast<const void*>(k_main),
                      hipFuncAttributeMaxDynamicSharedMemorySize, SMEM_BYTES);

  k_pack<<<NEXP * 3, 128, 0, stream>>>(W1, Wh, W1s, Whs, blob);
  k_fbuild<<<NEXP * 32, 256, 0, stream>>>(F_dist, F_cos, F_sin, Zd, Zc, Zs,
                                          IDX3, IDX5, F, Fs);
  k_main<<<NEXP * NTILE, 512, SMEM_BYTES, stream>>>(blob, F, Fs, b1, bh, Wo, bo,
                                                    b1s, bhs, Wos, bos, partial);
  k_reduce<<<NB / 256, 256, 0, stream>>>(partial, (float*)d_out);
}

// Round 5
// 288.343 us; speedup vs baseline: 1.4964x; 1.0110x over previous
//
#include <hip/hip_runtime.h>
#include <hip/hip_bf16.h>
#include <stdint.h>

#define NB 8192
#define NE 210
#define NS 7
#define NEXP 217
#define NI 8
#define H 128
#define BT 256
#define NTILE (NB / BT)          // 32
#define BLOB_STRIDE 69632        // 4K W1t(32B rows) + 32K Wh0t + 32K Wh1t
#define WH0_OFF 4096
#define WH1_OFF 36864
#define SMEM_BYTES 65536         // Wh only -> 2 blocks/CU

// ws layout (bytes)
#define O_BLOB 0u
#define O_F    16000000u
#define O_FS   43525120u
#define O_PART 43754496u

typedef __attribute__((ext_vector_type(8))) short bf16x8;
typedef __attribute__((ext_vector_type(4))) float f32x4;
typedef __attribute__((ext_vector_type(16))) float f32x16;
typedef __attribute__((ext_vector_type(2))) int i32x2;

union I4V { int4 i; bf16x8 v; unsigned u[4]; };

__device__ __forceinline__ unsigned short f2bf(float f) {
  unsigned u = __float_as_uint(f);
  u += 0x7fffu + ((u >> 16) & 1u);
  return (unsigned short)(u >> 16);
}
__device__ __forceinline__ float fast_tanh(float x) {
  // tanh(x) = 1 - 2/(1 + 2^(2*log2(e)*x)); saturates correctly at +-inf
  float e = __builtin_amdgcn_exp2f(2.8853900817779268f * x);
  return 1.0f - 2.0f * __builtin_amdgcn_rcpf(1.0f + e);
}
__device__ __forceinline__ unsigned pk_bf16(float a, float b) {
  unsigned r;
  asm("v_cvt_pk_bf16_f32 %0, %1, %2" : "=v"(r) : "v"(a), "v"(b));
  return r;
}
__device__ __forceinline__ void glds16(const void* g, void* l) {
  __builtin_amdgcn_global_load_lds(
      (const __attribute__((address_space(1))) unsigned int*)g,
      (__attribute__((address_space(3))) unsigned int*)l, 16, 0, 0);
}

// ---- inter-layer transition, all in registers (32x32 D-layout) -----------
// D: lane(hi=l>>5, col=l&31), reg r: feat = (r&3)+8*(r>>2)+4*hi (+32*ms)
// For k-slice kk (ms=kk>>1, ko=(kk&1)*8):
//   P0 = feats 16kk+{0,1}+4hi_s   P1 = 16kk+{2,3}+4hi_s
//   P2 = feats 16kk+8+{0,1}+4hi_s P3 = 16kk+8+{2,3}+4hi_s
// Next B-frag word w at dest lane hi_d needs feats 16kk+8hi_d+{2w,2w+1}:
//   w0 = {lo:P0@lo, hi:P2@lo}  w2 = {lo:P0@hi, hi:P2@hi}
//   w1 = {lo:P1@lo, hi:P3@lo}  w3 = {lo:P1@hi, hi:P3@hi}
// permlane32_swap(D,S): new_D = {D@lo, S@lo}, new_S = {D@hi, S@hi}
//   => swap(P0,P2) = (w0, w2); swap(P1,P3) = (w1, w3)
__device__ __forceinline__ void transition(const f32x16 (&acc)[4], bf16x8 (&bn)[8]) {
#pragma unroll
  for (int kk = 0; kk < 8; ++kk) {
    const int ms = kk >> 1, ko = (kk & 1) * 8;
    unsigned P0 = pk_bf16(fast_tanh(acc[ms][ko + 0]), fast_tanh(acc[ms][ko + 1]));
    unsigned P1 = pk_bf16(fast_tanh(acc[ms][ko + 2]), fast_tanh(acc[ms][ko + 3]));
    unsigned P2 = pk_bf16(fast_tanh(acc[ms][ko + 4]), fast_tanh(acc[ms][ko + 5]));
    unsigned P3 = pk_bf16(fast_tanh(acc[ms][ko + 6]), fast_tanh(acc[ms][ko + 7]));
    i32x2 s0 = __builtin_amdgcn_permlane32_swap((int)P0, (int)P2, false, false);
    i32x2 s1 = __builtin_amdgcn_permlane32_swap((int)P1, (int)P3, false, false);
    I4V r;
    r.u[0] = (unsigned)s0.x;   // w0
    r.u[1] = (unsigned)s1.x;   // w1
    r.u[2] = (unsigned)s0.y;   // w2
    r.u[3] = (unsigned)s1.y;   // w3
    bn[kk] = r.v;
  }
}

// ---------------- weight pack ---------------------------------------------
__global__ __launch_bounds__(128) void k_pack(
    const float* __restrict__ W1, const float* __restrict__ Wh,
    const float* __restrict__ W1s, const float* __restrict__ Whs,
    uint8_t* __restrict__ blob) {
  int bid = blockIdx.x;
  int e = bid / 3, sec = bid % 3;
  int n = threadIdx.x;
  uint8_t* be = blob + (size_t)e * BLOB_STRIDE;
  bool big = e < NE;
  int s = e - NE;
  if (sec == 0) {
    // W1t: 128 rows x 32B (K=16, real k 0..7, rest zero), linear
    union { int4 v[2]; unsigned short u[16]; } row;
    row.v[0] = make_int4(0, 0, 0, 0);
    row.v[1] = make_int4(0, 0, 0, 0);
    if (big) {
      for (int k = 0; k < NI; ++k) row.u[k] = f2bf(W1[((size_t)e * NI + k) * H + n]);
    } else {
      for (int k = 0; k < 2; ++k) row.u[k] = f2bf(W1s[((size_t)s * 2 + k) * H + n]);
    }
    *(int4*)(be + n * 32) = row.v[0];
    *(int4*)(be + n * 32 + 16) = row.v[1];
  } else {
    int l = sec - 1;
    union { int4 v[16]; unsigned short u[128]; } row;
    if (big) {
      for (int k = 0; k < H; ++k)
        row.u[k] = f2bf(Wh[(((size_t)l * NE + e) * H + k) * H + n]);
    } else {
      for (int k = 0; k < H; ++k)
        row.u[k] = f2bf(Whs[(((size_t)l * NS + s) * H + k) * H + n]);
    }
    int4* dst = (int4*)(be + (l ? WH1_OFF : WH0_OFF) + n * 256);
    for (int c = 0; c < 16; ++c) dst[c] = row.v[c ^ (n & 15)];
  }
}

// ---------------- F build: normalize + gather, bf16 -----------------------
__global__ __launch_bounds__(256) void k_fbuild(
    const float* __restrict__ F_dist, const float* __restrict__ F_cos,
    const float* __restrict__ F_sin,
    const float* __restrict__ Zd, const float* __restrict__ Zc,
    const float* __restrict__ Zs,
    const int* __restrict__ IDX3, const int* __restrict__ IDX5,
    uint16_t* __restrict__ F, uint16_t* __restrict__ Fs) {
  int bid = blockIdx.x;
  int e = bid >> 5, tile = bid & 31;
  int b = tile * 256 + threadIdx.x;
  if (e < NE) {
    float cv = (F_cos[(size_t)b * NE + e] - Zc[e]) / Zc[NE + e];
    float sv = (F_sin[(size_t)b * NE + e] - Zs[e]) / Zs[NE + e];
    union { int4 v; unsigned short u[8]; } o;
    for (int j = 0; j < 6; ++j) {
      int id = IDX3[e * 6 + j];
      float x = (F_dist[(size_t)b * 45 + id] - Zd[id]) / Zd[45 + id];
      o.u[j] = f2bf(x);
    }
    o.u[6] = f2bf(cv);
    o.u[7] = f2bf(sv);
    *(int4*)(F + ((size_t)e * NB + b) * 8) = o.v;
  } else {
    int s = e - NE;
    int id = IDX5[s];
    float cv = (F_cos[(size_t)b * NE + id] - Zc[id]) / Zc[NE + id];
    float sv = (F_sin[(size_t)b * NE + id] - Zs[id]) / Zs[NE + id];
    unsigned o = (unsigned)f2bf(cv) | ((unsigned)f2bf(sv) << 16);
    *(unsigned*)(Fs + ((size_t)s * NB + b) * 2) = o;
  }
}

// ---------------- main: 3-layer MLP, 32x32x16 MFMA, h in registers --------
__global__ __launch_bounds__(512, 4) void k_main(
    const uint8_t* __restrict__ blob,
    const uint16_t* __restrict__ F, const uint16_t* __restrict__ Fs,
    const float* __restrict__ b1, const float* __restrict__ bh,
    const float* __restrict__ Wo, const float* __restrict__ bo,
    const float* __restrict__ b1s, const float* __restrict__ bhs,
    const float* __restrict__ Wos, const float* __restrict__ bos,
    float* __restrict__ partial) {
  extern __shared__ __attribute__((aligned(16))) uint8_t smem[];  // 64KB Wh

  int bid = blockIdx.x;
  const int TOT = NEXP * NTILE;    // 6944, divisible by 8
  int lb = (bid & 7) * (TOT >> 3) + (bid >> 3);   // XCD-chunked swizzle
  int e = lb >> 5;
  int tile = lb & 31;
  int brow = tile * BT;

  int t = threadIdx.x;
  int w = t >> 6, lane = t & 63;
  int row = lane & 31, hi = lane >> 5;
  int hi4 = hi << 2;

  bool big = e < NE;
  int s = e - NE;
  const uint8_t* be = blob + (size_t)e * BLOB_STRIDE;

  // async Wh staging: 64 x 1KB chunks (the only LDS use; one barrier)
  for (int c = w; c < 64; c += 8)
    glds16(be + WH0_OFF + c * 1024 + lane * 16, smem + c * 1024);

  const float* bias1  = big ? b1 + (size_t)e * H : b1s + (size_t)s * H;
  const float* biasH0 = big ? bh + (size_t)e * H : bhs + (size_t)s * H;
  const float* biasH1 = big ? bh + ((size_t)NE + e) * H : bhs + ((size_t)NS + s) * H;
  const float* wo = big ? Wo + (size_t)e * H : Wos + (size_t)s * H;
  float bout = big ? bo[e] : bos[s];

  f32x16 acc[4];
  bf16x8 bn[8];

  // ---- layer 1 (K=16, real 8; hi=1 half all zero), no LDS ----
  {
    I4V bfr;
    bfr.i = make_int4(0, 0, 0, 0);
    if (hi == 0) {
      if (big) {
        bfr.i = *(const int4*)(F + ((size_t)e * NB + brow + w * 32 + row) * 8);
      } else {
        bfr.u[0] = *(const unsigned*)(Fs + ((size_t)s * NB + brow + w * 32 + row) * 2);
      }
    }
#pragma unroll
    for (int mt = 0; mt < 4; ++mt) {
      I4V a;
      a.i = *(const int4*)(be + (mt * 32 + row) * 32 + hi * 16);
      f32x16 c0;
#pragma unroll
      for (int i = 0; i < 4; ++i) {
        f32x4 q = *(const f32x4*)(bias1 + mt * 32 + i * 8 + hi4);
        c0[4 * i + 0] = q[0]; c0[4 * i + 1] = q[1];
        c0[4 * i + 2] = q[2]; c0[4 * i + 3] = q[3];
      }
      acc[mt] = __builtin_amdgcn_mfma_f32_32x32x16_bf16(a.v, bfr.v, c0, 0, 0, 0);
    }
  }

  transition(acc, bn);   // tanh + repack (registers only), overlaps staging

  __syncthreads();       // weights resident

  // ---- hidden layers (K=128, 8 k-slices of 16) ----
#pragma unroll
  for (int layer = 0; layer < 2; ++layer) {
    const uint8_t* wb = smem + layer * 32768;
    const float* bia = layer ? biasH1 : biasH0;
#pragma unroll
    for (int mt = 0; mt < 4; ++mt) {
#pragma unroll
      for (int i = 0; i < 4; ++i) {
        f32x4 q = *(const f32x4*)(bia + mt * 32 + i * 8 + hi4);
        acc[mt][4 * i + 0] = q[0]; acc[mt][4 * i + 1] = q[1];
        acc[mt][4 * i + 2] = q[2]; acc[mt][4 * i + 3] = q[3];
      }
    }
#pragma unroll
    for (int kk = 0; kk < 8; ++kk) {
      int soff = ((2 * kk + hi) ^ (row & 15)) << 4;
#pragma unroll
      for (int mt = 0; mt < 4; ++mt) {
        bf16x8 aF = *(const bf16x8*)(wb + (mt * 32 + row) * 256 + soff);
        acc[mt] = __builtin_amdgcn_mfma_f32_32x32x16_bf16(aF, bn[kk], acc[mt], 0, 0, 0);
      }
    }
    if (layer == 0)
      transition(acc, bn);
  }

  // ---- output layer: in-register dot, reduce across halves ---------------
  {
    float sum = 0.f;
#pragma unroll
    for (int mt = 0; mt < 4; ++mt)
#pragma unroll
      for (int i = 0; i < 4; ++i) {
        f32x4 wq = *(const f32x4*)(wo + mt * 32 + i * 8 + hi4);
#pragma unroll
        for (int j = 0; j < 4; ++j)
          sum += fast_tanh(acc[mt][4 * i + j]) * wq[j];
      }
    sum += __shfl_xor(sum, 32);
    if (hi == 0)
      partial[(size_t)e * NB + brow + w * 32 + row] = sum + bout;
  }
}

// ---------------- reduce over experts ------------------------------------
__global__ __launch_bounds__(256) void k_reduce(const float* __restrict__ partial,
                                                float* __restrict__ out) {
  int b = blockIdx.x * 256 + threadIdx.x;
  float s = 0.f;
  for (int e = 0; e < NEXP; ++e) s += partial[(size_t)e * NB + b];
  out[b] = s;
}

extern "C" void kernel_launch(void* const* d_in, const int* in_sizes, int n_in,
                              void* d_out, int out_size, void* d_ws, size_t ws_size,
                              hipStream_t stream) {
  const float* F_dist = (const float*)d_in[0];
  const float* F_cos  = (const float*)d_in[1];
  const float* F_sin  = (const float*)d_in[2];
  // d_in[3] F_angle unused by reference
  const float* Zd  = (const float*)d_in[4];
  const float* Zc  = (const float*)d_in[5];
  const float* Zs  = (const float*)d_in[6];
  const int* IDX3  = (const int*)d_in[7];
  const int* IDX5  = (const int*)d_in[8];
  const float* W1  = (const float*)d_in[9];
  const float* b1  = (const float*)d_in[10];
  const float* Wh  = (const float*)d_in[11];
  const float* bh  = (const float*)d_in[12];
  const float* Wo  = (const float*)d_in[13];
  const float* bo  = (const float*)d_in[14];
  const float* W1s = (const float*)d_in[15];
  const float* b1s = (const float*)d_in[16];
  const float* Whs = (const float*)d_in[17];
  const float* bhs = (const float*)d_in[18];
  const float* Wos = (const float*)d_in[19];
  const float* bos = (const float*)d_in[20];

  uint8_t* ws = (uint8_t*)d_ws;
  uint8_t* blob = ws + O_BLOB;
  uint16_t* F   = (uint16_t*)(ws + O_F);
  uint16_t* Fs  = (uint16_t*)(ws + O_FS);
  float* partial = (float*)(ws + O_PART);

  hipFuncSetAttribute(reinterpret_cast<const void*>(k_main),
                      hipFuncAttributeMaxDynamicSharedMemorySize, SMEM_BYTES);

  k_pack<<<NEXP * 3, 128, 0, stream>>>(W1, Wh, W1s, Whs, blob);
  k_fbuild<<<NEXP * 32, 256, 0, stream>>>(F_dist, F_cos, F_sin, Zd, Zc, Zs,
                                          IDX3, IDX5, F, Fs);
  k_main<<<NEXP * NTILE, 512, SMEM_BYTES, stream>>>(blob, F, Fs, b1, bh, Wo, bo,
                                                    b1s, bhs, Wos, bos, partial);
  k_reduce<<<NB / 256, 256, 0, stream>>>(partial, (float*)d_out);
}

// Round 7
// 270.388 us; speedup vs baseline: 1.5958x; 1.0664x over previous
//
#include <hip/hip_runtime.h>
#include <hip/hip_bf16.h>
#include <stdint.h>

#define NB 8192
#define NE 210
#define NS 7
#define NEXP 217
#define NI 8
#define H 128
#define BT 256
#define NTILE (NB / BT)          // 32
// blob per expert: [W1t 4K][bias 2K: bH0,bH1,wo,bout][Wh0 32K][Wh1 32K]
#define BLOB_STRIDE 71680
#define BIAS_OFF 4096
#define WH0_OFF 6144
#define WH1_OFF 38912
#define SMEM_BYTES 67584         // 2K bias + 64K Wh -> 2 blocks/CU

// ws layout (bytes)
#define O_BLOB 0u
#define O_F    16000000u
#define O_FS   43525120u
#define O_PART 43754496u

typedef __attribute__((ext_vector_type(8))) short bf16x8;
typedef __attribute__((ext_vector_type(4))) float f32x4;
typedef __attribute__((ext_vector_type(16))) float f32x16;
typedef __attribute__((ext_vector_type(2))) int i32x2;

union I4V { int4 i; bf16x8 v; unsigned u[4]; };
union C16 { f32x16 v; f32x4 q[4]; };

__device__ __forceinline__ unsigned short f2bf(float f) {
  unsigned u = __float_as_uint(f);
  u += 0x7fffu + ((u >> 16) & 1u);
  return (unsigned short)(u >> 16);
}
__device__ __forceinline__ float fast_tanh(float x) {
  // tanh(x) = 1 - 2/(1 + 2^(2*log2(e)*x)); saturates correctly at +-inf
  float e = __builtin_amdgcn_exp2f(2.8853900817779268f * x);
  return 1.0f - 2.0f * __builtin_amdgcn_rcpf(1.0f + e);
}
__device__ __forceinline__ unsigned pk_bf16(float a, float b) {
  unsigned r;
  asm("v_cvt_pk_bf16_f32 %0, %1, %2" : "=v"(r) : "v"(a), "v"(b));
  return r;
}
__device__ __forceinline__ void glds16(const void* g, void* l) {
  __builtin_amdgcn_global_load_lds(
      (const __attribute__((address_space(1))) unsigned int*)g,
      (__attribute__((address_space(3))) unsigned int*)l, 16, 0, 0);
}

// ---- inter-layer transition (verified R5 permlane mapping) ---------------
__device__ __forceinline__ void transition(const f32x16 (&acc)[4], bf16x8 (&bn)[8]) {
#pragma unroll
  for (int kk = 0; kk < 8; ++kk) {
    const int ms = kk >> 1, ko = (kk & 1) * 8;
    unsigned P0 = pk_bf16(fast_tanh(acc[ms][ko + 0]), fast_tanh(acc[ms][ko + 1]));
    unsigned P1 = pk_bf16(fast_tanh(acc[ms][ko + 2]), fast_tanh(acc[ms][ko + 3]));
    unsigned P2 = pk_bf16(fast_tanh(acc[ms][ko + 4]), fast_tanh(acc[ms][ko + 5]));
    unsigned P3 = pk_bf16(fast_tanh(acc[ms][ko + 6]), fast_tanh(acc[ms][ko + 7]));
    i32x2 s0 = __builtin_amdgcn_permlane32_swap((int)P0, (int)P2, false, false);
    i32x2 s1 = __builtin_amdgcn_permlane32_swap((int)P1, (int)P3, false, false);
    I4V r;
    r.u[0] = (unsigned)s0.x;   // w0
    r.u[1] = (unsigned)s1.x;   // w1
    r.u[2] = (unsigned)s0.y;   // w2
    r.u[3] = (unsigned)s1.y;   // w3
    bn[kk] = r.v;
  }
}

// ---- one hidden layer: K=128 as 8 k-slices; bias enters as C of kk=0 ------
__device__ __forceinline__ void hidden_layer(f32x16 (&acc)[4], const bf16x8 (&bn)[8],
                                             const uint8_t* wb, const float* biaL,
                                             int row, int hi, int hi4) {
  {
    int soff0 = (hi ^ (row & 15)) << 4;
#pragma unroll
    for (int mt = 0; mt < 4; ++mt) {
      bf16x8 aF = *(const bf16x8*)(wb + (mt * 32 + row) * 256 + soff0);
      C16 c0;
#pragma unroll
      for (int i = 0; i < 4; ++i)
        c0.q[i] = *(const f32x4*)(biaL + mt * 32 + i * 8 + hi4);
      acc[mt] = __builtin_amdgcn_mfma_f32_32x32x16_bf16(aF, bn[0], c0.v, 0, 0, 0);
    }
  }
#pragma unroll
  for (int kk = 1; kk < 8; ++kk) {
    int soff = ((2 * kk + hi) ^ (row & 15)) << 4;
#pragma unroll
    for (int mt = 0; mt < 4; ++mt) {
      bf16x8 aF = *(const bf16x8*)(wb + (mt * 32 + row) * 256 + soff);
      acc[mt] = __builtin_amdgcn_mfma_f32_32x32x16_bf16(aF, bn[kk], acc[mt], 0, 0, 0);
    }
  }
}

// ---------------- weight pack ---------------------------------------------
__global__ __launch_bounds__(128) void k_pack(
    const float* __restrict__ W1, const float* __restrict__ Wh,
    const float* __restrict__ W1s, const float* __restrict__ Whs,
    const float* __restrict__ bh, const float* __restrict__ bhs,
    const float* __restrict__ Wo, const float* __restrict__ Wos,
    const float* __restrict__ bo, const float* __restrict__ bos,
    uint8_t* __restrict__ blob) {
  int bid = blockIdx.x;
  int e = bid / 3, sec = bid % 3;
  int n = threadIdx.x;
  uint8_t* be = blob + (size_t)e * BLOB_STRIDE;
  bool big = e < NE;
  int s = e - NE;
  if (sec == 0) {
    // W1t: 128 rows x 32B (K=16, real k 0..7, rest zero), linear
    union { int4 v[2]; unsigned short u[16]; } row;
    row.v[0] = make_int4(0, 0, 0, 0);
    row.v[1] = make_int4(0, 0, 0, 0);
    if (big) {
      for (int k = 0; k < NI; ++k) row.u[k] = f2bf(W1[((size_t)e * NI + k) * H + n]);
    } else {
      for (int k = 0; k < 2; ++k) row.u[k] = f2bf(W1s[((size_t)s * 2 + k) * H + n]);
    }
    *(int4*)(be + n * 32) = row.v[0];
    *(int4*)(be + n * 32 + 16) = row.v[1];
    // bias section: bH0[128] | bH1[128] | wo[128] | bout
    float* bsec = (float*)(be + BIAS_OFF);
    bsec[n]       = big ? bh[(size_t)e * H + n]          : bhs[(size_t)s * H + n];
    bsec[128 + n] = big ? bh[((size_t)NE + e) * H + n]   : bhs[((size_t)NS + s) * H + n];
    bsec[256 + n] = big ? Wo[(size_t)e * H + n]          : Wos[(size_t)s * H + n];
    if (n == 0) bsec[384] = big ? bo[e] : bos[s];
  } else {
    int l = sec - 1;
    union { int4 v[16]; unsigned short u[128]; } row;
    if (big) {
      for (int k = 0; k < H; ++k)
        row.u[k] = f2bf(Wh[(((size_t)l * NE + e) * H + k) * H + n]);
    } else {
      for (int k = 0; k < H; ++k)
        row.u[k] = f2bf(Whs[(((size_t)l * NS + s) * H + k) * H + n]);
    }
    int4* dst = (int4*)(be + (l ? WH1_OFF : WH0_OFF) + n * 256);
    for (int c = 0; c < 16; ++c) dst[c] = row.v[c ^ (n & 15)];
  }
}

// ---------------- F build: normalize + gather, bf16 -----------------------
__global__ __launch_bounds__(256) void k_fbuild(
    const float* __restrict__ F_dist, const float* __restrict__ F_cos,
    const float* __restrict__ F_sin,
    const float* __restrict__ Zd, const float* __restrict__ Zc,
    const float* __restrict__ Zs,
    const int* __restrict__ IDX3, const int* __restrict__ IDX5,
    uint16_t* __restrict__ F, uint16_t* __restrict__ Fs) {
  int bid = blockIdx.x;
  int e = bid >> 5, tile = bid & 31;
  int b = tile * 256 + threadIdx.x;
  if (e < NE) {
    float cv = (F_cos[(size_t)b * NE + e] - Zc[e]) / Zc[NE + e];
    float sv = (F_sin[(size_t)b * NE + e] - Zs[e]) / Zs[NE + e];
    union { int4 v; unsigned short u[8]; } o;
    for (int j = 0; j < 6; ++j) {
      int id = IDX3[e * 6 + j];
      float x = (F_dist[(size_t)b * 45 + id] - Zd[id]) / Zd[45 + id];
      o.u[j] = f2bf(x);
    }
    o.u[6] = f2bf(cv);
    o.u[7] = f2bf(sv);
    *(int4*)(F + ((size_t)e * NB + b) * 8) = o.v;
  } else {
    int s = e - NE;
    int id = IDX5[s];
    float cv = (F_cos[(size_t)b * NE + id] - Zc[id]) / Zc[NE + id];
    float sv = (F_sin[(size_t)b * NE + id] - Zs[id]) / Zs[NE + id];
    unsigned o = (unsigned)f2bf(cv) | ((unsigned)f2bf(sv) << 16);
    *(unsigned*)(Fs + ((size_t)s * NB + b) * 2) = o;
  }
}

// ---------------- main: 3-layer MLP, 32x32x16 MFMA, h in registers --------
__global__ __launch_bounds__(512, 4) void k_main(
    const uint8_t* __restrict__ blob,
    const uint16_t* __restrict__ F, const uint16_t* __restrict__ Fs,
    const float* __restrict__ b1, const float* __restrict__ b1s,
    float* __restrict__ partial) {
  extern __shared__ __attribute__((aligned(16))) uint8_t smem[];
  // smem: [0:2K bias/wo][2048: Wh0 32K][34816: Wh1 32K]

  int bid = blockIdx.x;
  const int TOT = NEXP * NTILE;    // 6944, divisible by 8
  int lb = (bid & 7) * (TOT >> 3) + (bid >> 3);   // XCD-chunked swizzle
  int e = lb >> 5;
  int tile = lb & 31;
  int brow = tile * BT;

  int t = threadIdx.x;
  int w = t >> 6, lane = t & 63;
  int row = lane & 31, hi = lane >> 5;
  int hi4 = hi << 2;

  bool big = e < NE;
  int s = e - NE;
  const uint8_t* be = blob + (size_t)e * BLOB_STRIDE;

  // ---- early VMEM (issued BEFORE glds: in-order vmcnt => waiting on these
  //      does not drain the staging queue; L1+transition overlap staging) ----
  I4V bfr;
  bfr.i = make_int4(0, 0, 0, 0);
  if (hi == 0) {
    if (big) {
      bfr.i = *(const int4*)(F + ((size_t)e * NB + brow + w * 32 + row) * 8);
    } else {
      bfr.u[0] = *(const unsigned*)(Fs + ((size_t)s * NB + brow + w * 32 + row) * 2);
    }
  }
  const float* bias1 = big ? b1 + (size_t)e * H : b1s + (size_t)s * H;
  I4V aW[4];
  C16 c1[4];
#pragma unroll
  for (int mt = 0; mt < 4; ++mt) {
    aW[mt].i = *(const int4*)(be + (mt * 32 + row) * 32 + hi * 16);
#pragma unroll
    for (int i = 0; i < 4; ++i)
      c1[mt].q[i] = *(const f32x4*)(bias1 + mt * 32 + i * 8 + hi4);
  }
  __builtin_amdgcn_sched_barrier(0);

  // ---- phase A staging: bias(2) + Wh0(32) chunks; phase B: Wh1(32) -------
  for (int c = w; c < 34; c += 8)
    glds16(be + BIAS_OFF + c * 1024 + lane * 16, smem + c * 1024);
  __builtin_amdgcn_sched_barrier(0);
  for (int c = 34 + w; c < 66; c += 8)
    glds16(be + BIAS_OFF + c * 1024 + lane * 16, smem + c * 1024);
  __builtin_amdgcn_sched_barrier(0);

  // ---- layer 1 (K=16, real 8; hi=1 half zero), no LDS: overlaps staging --
  f32x16 acc[4];
#pragma unroll
  for (int mt = 0; mt < 4; ++mt)
    acc[mt] = __builtin_amdgcn_mfma_f32_32x32x16_bf16(aW[mt].v, bfr.v, c1[mt].v, 0, 0, 0);

  bf16x8 bn[8];
  transition(acc, bn);

  // A done (the 4 youngest VMEM ops are always the Wh1 glds) -> layer 0 can
  // run while Wh1 is still in flight.
  asm volatile("s_waitcnt vmcnt(4)" ::: "memory");
  __builtin_amdgcn_s_barrier();
  __builtin_amdgcn_sched_barrier(0);

  hidden_layer(acc, bn, smem + 2048, (const float*)smem, row, hi, hi4);
  transition(acc, bn);

  asm volatile("s_waitcnt vmcnt(0)" ::: "memory");
  __builtin_amdgcn_s_barrier();
  __builtin_amdgcn_sched_barrier(0);

  hidden_layer(acc, bn, smem + 34816, (const float*)(smem + 512), row, hi, hi4);

  // ---- output layer: in-register dot (wo/bout from staged LDS) -----------
  {
    const float* woL = (const float*)(smem + 1024);
    float bout = *(const float*)(smem + 1536);
    float sum = 0.f;
#pragma unroll
    for (int mt = 0; mt < 4; ++mt)
#pragma unroll
      for (int i = 0; i < 4; ++i) {
        f32x4 wq = *(const f32x4*)(woL + mt * 32 + i * 8 + hi4);
#pragma unroll
        for (int j = 0; j < 4; ++j)
          sum += fast_tanh(acc[mt][4 * i + j]) * wq[j];
      }
    sum += __shfl_xor(sum, 32);
    if (hi == 0)
      partial[(size_t)e * NB + brow + w * 32 + row] = sum + bout;
  }
}

// ---------------- reduce over experts ------------------------------------
__global__ __launch_bounds__(256) void k_reduce(const float* __restrict__ partial,
                                                float* __restrict__ out) {
  int b = blockIdx.x * 256 + threadIdx.x;
  float s = 0.f;
  for (int e = 0; e < NEXP; ++e) s += partial[(size_t)e * NB + b];
  out[b] = s;
}

extern "C" void kernel_launch(void* const* d_in, const int* in_sizes, int n_in,
                              void* d_out, int out_size, void* d_ws, size_t ws_size,
                              hipStream_t stream) {
  const float* F_dist = (const float*)d_in[0];
  const float* F_cos  = (const float*)d_in[1];
  const float* F_sin  = (const float*)d_in[2];
  // d_in[3] F_angle unused by reference
  const float* Zd  = (const float*)d_in[4];
  const float* Zc  = (const float*)d_in[5];
  const float* Zs  = (const float*)d_in[6];
  const int* IDX3  = (const int*)d_in[7];
  const int* IDX5  = (const int*)d_in[8];
  const float* W1  = (const float*)d_in[9];
  const float* b1  = (const float*)d_in[10];
  const float* Wh  = (const float*)d_in[11];
  const float* bh  = (const float*)d_in[12];
  const float* Wo  = (const float*)d_in[13];
  const float* bo  = (const float*)d_in[14];
  const float* W1s = (const float*)d_in[15];
  const float* b1s = (const float*)d_in[16];
  const float* Whs = (const float*)d_in[17];
  const float* bhs = (const float*)d_in[18];
  const float* Wos = (const float*)d_in[19];
  const float* bos = (const float*)d_in[20];

  uint8_t* ws = (uint8_t*)d_ws;
  uint8_t* blob = ws + O_BLOB;
  uint16_t* F   = (uint16_t*)(ws + O_F);
  uint16_t* Fs  = (uint16_t*)(ws + O_FS);
  float* partial = (float*)(ws + O_PART);

  hipFuncSetAttribute(reinterpret_cast<const void*>(k_main),
                      hipFuncAttributeMaxDynamicSharedMemorySize, SMEM_BYTES);

  k_pack<<<NEXP * 3, 128, 0, stream>>>(W1, Wh, W1s, Whs, bh, bhs, Wo, Wos, bo, bos, blob);
  k_fbuild<<<NEXP * 32, 256, 0, stream>>>(F_dist, F_cos, F_sin, Zd, Zc, Zs,
                                          IDX3, IDX5, F, Fs);
  k_main<<<NEXP * NTILE, 512, SMEM_BYTES, stream>>>(blob, F, Fs, b1, b1s, partial);
  k_reduce<<<NB / 256, 256, 0, stream>>>(partial, (float*)d_out);
}